// Round 14
// baseline (308.224 us; speedup 1.0000x reference)
//
#include <hip/hip_runtime.h>

#define NB 128
#define NT 512
#define NL 256
#define NWG NB           // one workgroup per batch

typedef float f32x4 __attribute__((ext_vector_type(4)));
typedef int   i32x8 __attribute__((ext_vector_type(8)));

#define EASTRIDE 272     // bytes per EA buffer (256 + 16 pad, 16B aligned)
#define GEXP 7           // a-priori per-step log2 growth estimate
#define E8M0_ONE 127     // e8m0 encoding of 1.0 for mfma_scale
#define INV_LN2 1.4426950408889634f
#define LN2 0.6931471805599453f

__device__ inline float log2_fast(float x) {
#if __has_builtin(__builtin_amdgcn_logf)
    return __builtin_amdgcn_logf(x);
#else
    return __log2f(x);
#endif
}
__device__ inline float exp2_fast(float x) {
#if __has_builtin(__builtin_amdgcn_exp2f)
    return __builtin_amdgcn_exp2f(x);
#else
    return exp2f(x);
#endif
}

// Barrier that waits only on LDS/SMEM ops — prefetch global loads stay in flight.
__device__ inline void barrier_lds_only() {
    asm volatile("s_waitcnt lgkmcnt(0)" ::: "memory");
    __builtin_amdgcn_s_barrier();
    asm volatile("" ::: "memory");
}

// pack 4 f32 -> 4 fp8 e4m3 bytes (saturating)
__device__ inline unsigned pk_fp8x4(float a, float b, float c, float d) {
    int w = __builtin_amdgcn_cvt_pk_fp8_f32(a, b, 0, false);
    w     = __builtin_amdgcn_cvt_pk_fp8_f32(c, d, w, true);
    return (unsigned)w;
}

// One WG (512 thr = 8 waves, 2 waves/SIMD) per batch.  Numerics identical to
// r8-r13 (absmax 0.0 five rounds): exp-space recurrence, damped power-of-2
// normalization from a one-step-stale max, S accumulates exact integer
// exponents.  r13 post-mortem: VALU-issue bound (~660 cy/SIMD/step measured
// vs ~120 algorithmic).  This round is a codegen-lean rewrite of the SAME
// algorithm: no eC register copies (ex computed before PF reload), direct
// i32x8 LDS reinterpret for B-frags (no element moves), scalar s_load word
// pipeline (no wlds LDS), SGPR-based emission addressing, prefetch depth 2.
// Layout (16x16x128, shape-determined): A row=lane&15, k=(lane>>4)*32+j;
// B col=lane&15 (batch dup), k=(lane>>4)*32+j; D col=lane&15, row=g*4+reg.
__global__ __launch_bounds__(512, 2) void crf_forward(
    const float* __restrict__ emis,
    const float* __restrict__ trans,
    const int*   __restrict__ words,
    float*       __restrict__ bout)
{
    const int tid = threadIdx.x;
    const int l   = tid & 63;
    const int wv  = tid >> 6;    // 0..7
    const int g   = l >> 4;      // 0..3
    const int b   = l & 15;

    __shared__ __align__(16) unsigned char ea[2][EASTRIDE]; // fp8 EA, dbuf
    __shared__ __align__(16) float pm[2][8];                // per-wave stale maxes

    const int* ws = words + (size_t)blockIdx.x * NT;  // uniform base -> s_load
    const int eoff = wv * 32 + g * 4;                 // lane offset into emis row

    // ---- A-fragments: exp(trans) rows wv*32 + T*16 + b, K=128 layout ----
    i32x8 afr[2][2];
    #pragma unroll
    for (int T = 0; T < 2; ++T) {
        const int row = wv * 32 + T * 16 + b;
        #pragma unroll
        for (int kt = 0; kt < 2; ++kt) {
            const float* src = trans + row * NL + kt * 128 + g * 32;
            i32x8 a;
            #pragma unroll
            for (int w = 0; w < 8; ++w) {
                float4 v = *reinterpret_cast<const float4*>(src + w * 4);
                a[w] = (int)pk_fp8x4(__expf(v.x), __expf(v.y),
                                     __expf(v.z), __expf(v.w));
            }
            afr[T][kt] = a;
        }
    }

    // ---- word pipeline: 2-deep emission prefetch, scalar indices ----
    const int w0 = ws[0];
    const int w1 = ws[1];
    const int w2 = ws[2];
    int wA = ws[3];
    int wB = ws[4];

    float S = 0.f;   // exponent accumulator (exact small ints, same in all lanes)

    // ---- t=0 : EA_0 = fp8(2^(e0*INV_LN2)), rows wv*32 + T*16 + g*4 + j ----
    {
        const float* e0 = emis + (size_t)w0 * NL + eoff;
        f32x4 v0 = *reinterpret_cast<const f32x4*>(e0);
        f32x4 v1 = *reinterpret_cast<const f32x4*>(e0 + 16);
        float p00 = exp2_fast(v0[0] * INV_LN2), p01 = exp2_fast(v0[1] * INV_LN2);
        float p02 = exp2_fast(v0[2] * INV_LN2), p03 = exp2_fast(v0[3] * INV_LN2);
        float p10 = exp2_fast(v1[0] * INV_LN2), p11 = exp2_fast(v1[1] * INV_LN2);
        float p12 = exp2_fast(v1[2] * INV_LN2), p13 = exp2_fast(v1[3] * INV_LN2);
        float pmax = fmaxf(fmaxf(fmaxf(p00, p01), fmaxf(p02, p03)),
                           fmaxf(fmaxf(p10, p11), fmaxf(p12, p13)));
        pmax = fmaxf(pmax, __shfl_xor(pmax, 16));
        pmax = fmaxf(pmax, __shfl_xor(pmax, 32));
        if (l == 0) pm[0][wv] = pmax;
        if (b == 0) {
            *reinterpret_cast<unsigned*>(&ea[0][wv * 32 + g * 4]) =
                pk_fp8x4(p00, p01, p02, p03);
            *reinterpret_cast<unsigned*>(&ea[0][wv * 32 + 16 + g * 4]) =
                pk_fp8x4(p10, p11, p12, p13);
        }
    }
    f32x4 pfA0, pfA1, pfB0, pfB1;
    {
        const float* p1 = emis + (size_t)w1 * NL + eoff;
        pfA0 = *reinterpret_cast<const f32x4*>(p1);
        pfA1 = *reinterpret_cast<const f32x4*>(p1 + 16);
        const float* p2 = emis + (size_t)w2 * NL + eoff;
        pfB0 = *reinterpret_cast<const f32x4*>(p2);
        pfB1 = *reinterpret_cast<const f32x4*>(p2 + 16);
    }
    barrier_lds_only();

#define CRF_STEP(t, RD, WR, PF0, PF1, WREG)                                     \
    {                                                                           \
        /* B-frags + stale pm: all LDS reads issued together */                 \
        i32x8 bq0 = *reinterpret_cast<const i32x8*>(&ea[RD][g * 32]);           \
        i32x8 bq1 = *reinterpret_cast<const i32x8*>(&ea[RD][128 + g * 32]);     \
        f32x4 pm0 = *reinterpret_cast<const f32x4*>(&pm[RD][0]);                \
        f32x4 pm1 = *reinterpret_cast<const f32x4*>(&pm[RD][4]);                \
        float gm = fmaxf(fmaxf(fmaxf(pm0[0], pm0[1]), fmaxf(pm0[2], pm0[3])),   \
                         fmaxf(fmaxf(pm1[0], pm1[1]), fmaxf(pm1[2], pm1[3])));  \
        int   kb = (int)(__builtin_bit_cast(unsigned, gm) >> 23) - (127 - GEXP);\
        S += (float)kb;                                                         \
        float kbf = (float)kb;                                                  \
        /* ex from current PF regs (emission for step t), then reload PF */     \
        float exa0 = exp2_fast(fmaf(PF0[0], INV_LN2, -kbf));                    \
        float exa1 = exp2_fast(fmaf(PF0[1], INV_LN2, -kbf));                    \
        float exa2 = exp2_fast(fmaf(PF0[2], INV_LN2, -kbf));                    \
        float exa3 = exp2_fast(fmaf(PF0[3], INV_LN2, -kbf));                    \
        float exb0 = exp2_fast(fmaf(PF1[0], INV_LN2, -kbf));                    \
        float exb1 = exp2_fast(fmaf(PF1[1], INV_LN2, -kbf));                    \
        float exb2 = exp2_fast(fmaf(PF1[2], INV_LN2, -kbf));                    \
        float exb3 = exp2_fast(fmaf(PF1[3], INV_LN2, -kbf));                    \
        if ((t) + 2 < NT) {                                                     \
            const float* ep = emis + (size_t)WREG * NL + eoff;                  \
            PF0 = *reinterpret_cast<const f32x4*>(ep);                          \
            PF1 = *reinterpret_cast<const f32x4*>(ep + 16);                     \
        }                                                                       \
        if ((t) + 4 < NT) WREG = ws[(t) + 4];                                   \
        /* 2 parallel depth-2 scale-MFMA chains (K=128 each) */                 \
        f32x4 z0 = {0.f, 0.f, 0.f, 0.f};                                        \
        f32x4 z1 = {0.f, 0.f, 0.f, 0.f};                                        \
        z0 = __builtin_amdgcn_mfma_scale_f32_16x16x128_f8f6f4(                  \
                 afr[0][0], bq0, z0, 0, 0, 0, E8M0_ONE, 0, E8M0_ONE);           \
        z1 = __builtin_amdgcn_mfma_scale_f32_16x16x128_f8f6f4(                  \
                 afr[1][0], bq0, z1, 0, 0, 0, E8M0_ONE, 0, E8M0_ONE);           \
        z0 = __builtin_amdgcn_mfma_scale_f32_16x16x128_f8f6f4(                  \
                 afr[0][1], bq1, z0, 0, 0, 0, E8M0_ONE, 0, E8M0_ONE);           \
        z1 = __builtin_amdgcn_mfma_scale_f32_16x16x128_f8f6f4(                  \
                 afr[1][1], bq1, z1, 0, 0, 0, E8M0_ONE, 0, E8M0_ONE);           \
        float v00 = z0[0] * exa0, v01 = z0[1] * exa1;                           \
        float v02 = z0[2] * exa2, v03 = z0[3] * exa3;                           \
        float v10 = z1[0] * exb0, v11 = z1[1] * exb1;                           \
        float v12 = z1[2] * exb2, v13 = z1[3] * exb3;                           \
        float pmax = fmaxf(fmaxf(fmaxf(v00, v01), fmaxf(v02, v03)),             \
                           fmaxf(fmaxf(v10, v11), fmaxf(v12, v13)));            \
        pmax = fmaxf(pmax, __shfl_xor(pmax, 16));                               \
        pmax = fmaxf(pmax, __shfl_xor(pmax, 32));                               \
        if (l == 0) pm[WR][wv] = pmax;                                          \
        if (b == 0) {                                                           \
            *reinterpret_cast<unsigned*>(&ea[WR][wv * 32 + g * 4]) =            \
                pk_fp8x4(v00, v01, v02, v03);                                   \
            *reinterpret_cast<unsigned*>(&ea[WR][wv * 32 + 16 + g * 4]) =       \
                pk_fp8x4(v10, v11, v12, v13);                                   \
        }                                                                       \
        barrier_lds_only();                                                     \
    }

    for (int t = 1; t + 1 < NT; t += 2) {
        CRF_STEP(t,     0, 1, pfA0, pfA1, wA);
        CRF_STEP(t + 1, 1, 0, pfB0, pfB1, wB);
    }
    CRF_STEP(511, 0, 1, pfA0, pfA1, wA);   // final EA lands in ea[1]
#undef CRF_STEP

    // ---- final: logZ_b = ln2 * (S + log2(sum_k EA_last[k])) ----
    if (tid < 64) {
        unsigned u = *reinterpret_cast<const unsigned*>(&ea[1][tid * 4]);
        float s = __builtin_amdgcn_cvt_f32_fp8((int)u, 0)
                + __builtin_amdgcn_cvt_f32_fp8((int)u, 1)
                + __builtin_amdgcn_cvt_f32_fp8((int)u, 2)
                + __builtin_amdgcn_cvt_f32_fp8((int)u, 3);
        #pragma unroll
        for (int off = 32; off; off >>= 1) s += __shfl_xor(s, off);
        if (tid == 0) bout[blockIdx.x] = (S + log2_fast(s)) * LN2;
    }
}

__global__ void crf_reduce(const float* __restrict__ bout, float* __restrict__ out)
{
    const int tid = threadIdx.x;  // 128 threads
    float v = bout[tid];
    #pragma unroll
    for (int off = 32; off; off >>= 1) v += __shfl_xor(v, off);
    __shared__ float sred[2];
    if ((tid & 63) == 0) sred[tid >> 6] = v;
    __syncthreads();
    if (tid == 0) out[0] = sred[0] + sred[1];
}

extern "C" void kernel_launch(void* const* d_in, const int* in_sizes, int n_in,
                              void* d_out, int out_size, void* d_ws, size_t ws_size,
                              hipStream_t stream)
{
    const float* emis  = (const float*)d_in[0];
    const float* trans = (const float*)d_in[1];
    const int*   words = (const int*)d_in[2];
    float* out  = (float*)d_out;
    float* bout = (float*)d_ws;   // NWG floats of scratch

    crf_forward<<<NWG, 512, 0, stream>>>(emis, trans, words, bout);
    crf_reduce<<<1, NB, 0, stream>>>(bout, out);
}